// Round 14
// baseline (1298.894 us; speedup 1.0000x reference)
//
#include <hip/hip_runtime.h>
#include <hip/hip_bf16.h>

typedef __bf16 bf16_t;
typedef __bf16 bf16x8 __attribute__((ext_vector_type(8)));
typedef float f32x4 __attribute__((ext_vector_type(4)));

#define DI __device__ __forceinline__

static constexpr int TOK = 131072;  // 32 batches * 64*64 tokens
static constexpr int NWIN = 2048;   // 32 * 64 windows

// window-order token t -> source image token (LN1 gather) == proj scatter dest.
DI int src_token(int t) {
  int b = t >> 12;
  int widx = (t >> 6) & 63;
  int n = t & 63;
  int wh = widx >> 3, ww = widx & 7;
  int i = n >> 3, j = n & 7;
  int y = ((wh << 3) + i + 4) & 63;
  int x2 = ((ww << 3) + j + 4) & 63;
  return (b << 12) + (y << 6) + x2;
}

DI f32x4 mfma16(bf16x8 a, bf16x8 b, f32x4 c) {
  return __builtin_amdgcn_mfma_f32_16x16x32_bf16(a, b, c, 0, 0, 0);
}

DI void gload_lds16(const bf16_t* g, bf16_t* l) {
  __builtin_amdgcn_global_load_lds(
      (__attribute__((address_space(1))) void*)const_cast<bf16_t*>(g),
      (__attribute__((address_space(3))) void*)l, 16, 0, 0);
}

// ------ merged weight transpose+convert (+Q-scale fold, +scaled b_qkv) ------
__global__ void wconv_all(const float* __restrict__ wq, const float* __restrict__ wp,
                          const float* __restrict__ w1, const float* __restrict__ w2,
                          const float* __restrict__ bq,
                          bf16_t* oq, bf16_t* op_, bf16_t* o1, bf16_t* o2,
                          float* bqs) {
  int idx = blockIdx.x * 256 + threadIdx.x;
  const float s = 0.17677669529663687f;  // 32^-0.5
  if (idx < 442368) {
    int n = idx / 384, k = idx - n * 384;
    float v = wq[(size_t)k * 1152 + n];
    if (n < 384) v *= s;
    oq[idx] = (bf16_t)v;
  } else if ((idx -= 442368) < 147456) {
    int n = idx / 384, k = idx - n * 384;
    op_[idx] = (bf16_t)wp[(size_t)k * 384 + n];
  } else if ((idx -= 147456) < 589824) {
    int n = idx / 384, k = idx - n * 384;
    o1[idx] = (bf16_t)w1[(size_t)k * 1536 + n];
  } else if ((idx -= 589824) < 589824) {
    int n = idx / 1536, k = idx - n * 1536;
    o2[idx] = (bf16_t)w2[(size_t)k * 384 + n];
  } else if ((idx -= 589824) < 1152) {
    bqs[idx] = bq[idx] * (idx < 384 ? s : 1.f);
  }
}

// ------ bias_full[4 classes][12 heads][64][64] = rel_bias + shift-mask ------
__global__ void bias_build(const float* __restrict__ btab, float* __restrict__ bf) {
  int idx = blockIdx.x * 256 + threadIdx.x;  // < 4*12*4096
  int c = idx & 63, r = (idx >> 6) & 63;
  int hh = idx >> 12;
  int h = hh % 12, cls = hh / 12;
  int i1 = r >> 3, j1 = r & 7, i2 = c >> 3, j2 = c & 7;
  float v = btab[((i1 - i2 + 7) * 15 + (j1 - j2 + 7)) * 12 + h];
  int wh7 = cls >> 1, ww7 = cls & 1;
  int ly1 = wh7 ? (i1 >= 4 ? 2 : 1) : 0;
  int ly2 = wh7 ? (i2 >= 4 ? 2 : 1) : 0;
  int lx1 = ww7 ? (j1 >= 4 ? 2 : 1) : 0;
  int lx2 = ww7 ? (j2 >= 4 ? 2 : 1) : 0;
  if (ly1 != ly2 || lx1 != lx2) v -= 100.f;
  bf[idx] = v;
}

// ---------------- LayerNorm (+optional shift/partition gather), f32 -> bf16 --
template <int MAP>
__global__ __launch_bounds__(256)
void ln_kernel(const float* __restrict__ xin, const float* __restrict__ g,
               const float* __restrict__ be, bf16_t* __restrict__ out) {
  int w = threadIdx.x >> 6, l = threadIdx.x & 63;
  int t = blockIdx.x * 4 + w;
  int s = MAP ? src_token(t) : t;
  const float* row = xin + (size_t)s * 384;
  float v[6], s1 = 0.f, s2 = 0.f;
#pragma unroll
  for (int i = 0; i < 6; i++) {
    v[i] = row[l + i * 64];
    s1 += v[i];
    s2 += v[i] * v[i];
  }
#pragma unroll
  for (int o = 32; o; o >>= 1) {
    s1 += __shfl_xor(s1, o);
    s2 += __shfl_xor(s2, o);
  }
  float mean = s1 * (1.f / 384.f);
  float var = s2 * (1.f / 384.f) - mean * mean;
  float rs = rsqrtf(var + 1e-5f);
  bf16_t* orow = out + (size_t)t * 384;
#pragma unroll
  for (int i = 0; i < 6; i++) {
    int idx = l + i * 64;
    orow[idx] = (bf16_t)((v[i] - mean) * rs * g[idx] + be[idx]);
  }
}

// ---------------- GEMM: C[M][N] = A[M][K]*Wt[N][K]^T + bias ------------------
// r9-proven sync structure (single-buffered LDS, BK=64, 2 barriers/K-tile,
// both-sides XOR swizzle, XCD-chunked remap, VALU diet) with BIGGER per-wave
// tile: BM=256 x BN=128, 4 waves each owning 128x64 (8x4 fragments).
// Rationale (measured): at 4x4 frags, LDS traffic/MFMA ties the LDS port with
// the MFMA pipe; 8x4 frags cut reads/MFMA 25% and halve block-tile barrier
// periods per output element. acc=128 VGPRs; ~210 total; no spill at 2/CU.
// MODE 0: bf16 out. 1: bf16 gelu(out). 2: f32 scatter(src_token)+resid.
// MODE 3: f32 +resid (resid aliases outf; element owned by one thread).
template <int MODE>
__global__ __launch_bounds__(256, 2)
void gemm_bt(const bf16_t* __restrict__ A, const bf16_t* __restrict__ Wt,
             const float* __restrict__ bias, int K, int ldout, int ncols,
             bf16_t* outb, float* outf, const float* resid) {
  __shared__ __align__(16) bf16_t Alds[256 * 64];  // 32 KB
  __shared__ __align__(16) bf16_t Blds[128 * 64];  // 16 KB
  const int tid = threadIdx.x;
  const int l = tid & 63, w = tid >> 6;
  const int lr = l & 15, lq = l >> 4;
  // XCD-chunked bijective remap (nwg % 8 == 0)
  const int nwg = gridDim.x;
  const int orig = blockIdx.x;
  const int wgid = (orig & 7) * (nwg >> 3) + (orig >> 3);
  const int bn = wgid % ncols, bm = wgid / ncols;
  const int wr = w >> 1, wc = w & 1;

  // staging source (lane-dependent, swizzle-inverted): staged row & 7 == l>>3
  // (w*8 and r*32 are 0 mod 8), so the inverse-swizzled column is lane-only.
  const int srow = w * 8 + (l >> 3);
  const int scol = ((l & 7) ^ (l >> 3)) << 3;
  const bf16_t* ga = A + ((size_t)bm * 256 + srow) * K + scol;
  const bf16_t* gb = Wt + ((size_t)bn * 128 + srow) * K + scol;
  const size_t k32 = (size_t)32 * K;
  bf16_t* la = &Alds[w * 512];  // wave-uniform LDS dest base
  bf16_t* lb = &Blds[w * 512];

  // K-invariant swizzled LDS read element-offsets (ks=0; ks=1 is ^32)
  int aoff[8], boff[4];
#pragma unroll
  for (int fi = 0; fi < 8; fi++) {
    int ra = wr * 128 + fi * 16 + lr;
    aoff[fi] = ra * 64 + ((lq * 8) ^ ((ra & 7) << 3));
  }
#pragma unroll
  for (int fj = 0; fj < 4; fj++) {
    int rb = wc * 64 + fj * 16 + lr;
    boff[fj] = rb * 64 + ((lq * 8) ^ ((rb & 7) << 3));
  }

  f32x4 acc[8][4] = {};
  const int nt = K >> 6;
  for (int t = 0; t < nt; t++) {
#pragma unroll
    for (int r = 0; r < 8; r++)
      gload_lds16(ga + r * k32, la + r * 2048);
#pragma unroll
    for (int r = 0; r < 4; r++)
      gload_lds16(gb + r * k32, lb + r * 2048);
    ga += 64;
    gb += 64;
    __syncthreads();
#pragma unroll
    for (int ks = 0; ks < 2; ks++) {
      bf16x8 af[8], bfr[4];
#pragma unroll
      for (int fi = 0; fi < 8; fi++)
        af[fi] = *(const bf16x8*)&Alds[aoff[fi] ^ (ks * 32)];
#pragma unroll
      for (int fj = 0; fj < 4; fj++)
        bfr[fj] = *(const bf16x8*)&Blds[boff[fj] ^ (ks * 32)];
#pragma unroll
      for (int fi = 0; fi < 8; fi++)
#pragma unroll
        for (int fj = 0; fj < 4; fj++)
          acc[fi][fj] = mfma16(af[fi], bfr[fj], acc[fi][fj]);
    }
    __syncthreads();
  }

  // ---- epilogue ----
  float bv[4];
#pragma unroll
  for (int fj = 0; fj < 4; fj++)
    bv[fj] = bias[bn * 128 + wc * 64 + fj * 16 + lr];
#pragma unroll
  for (int fi = 0; fi < 8; fi++) {
#pragma unroll
    for (int reg = 0; reg < 4; reg++) {
      int grow = bm * 256 + wr * 128 + fi * 16 + lq * 4 + reg;
      size_t rbase;
      if constexpr (MODE == 2)
        rbase = (size_t)src_token(grow) * ldout;
      else
        rbase = (size_t)grow * ldout;
#pragma unroll
      for (int fj = 0; fj < 4; fj++) {
        int gcol = bn * 128 + wc * 64 + fj * 16 + lr;
        float val = acc[fi][fj][reg] + bv[fj];
        if constexpr (MODE == 0) {
          outb[rbase + gcol] = (bf16_t)val;
        } else if constexpr (MODE == 1) {
          // tanh-form GELU via fast sigmoid (rcp instead of div)
          float z = -1.5957691216f * val * fmaf(0.044715f, val * val, 1.0f);
          val = val * __builtin_amdgcn_rcpf(1.0f + __expf(z));
          outb[rbase + gcol] = (bf16_t)val;
        } else {
          outf[rbase + gcol] = val + resid[rbase + gcol];
        }
      }
    }
  }
}

// ---------------- per-(window, head) attention (r13: staging + bias table) --
__global__ __launch_bounds__(64)
void attn_kernel(const bf16_t* __restrict__ qkv, const float* __restrict__ biasF,
                 bf16_t* __restrict__ aout) {
  __shared__ __align__(16) bf16_t Qs[64 * 32];
  __shared__ __align__(16) bf16_t Ks[64 * 32];
  __shared__ __align__(16) bf16_t Vt[32 * 64];
  __shared__ __align__(16) bf16_t Ps[64 * 64];
  const int win = blockIdx.x, h = blockIdx.y;
  const int l = threadIdx.x, lr = l & 15, lq = l >> 4;

  {
    const bf16_t* qrow = qkv + ((size_t)win * 64 + l) * 1152 + h * 32;
#pragma unroll
    for (int c = 0; c < 4; c++) {
      *(bf16x8*)&Qs[l * 32 + c * 8] = *(const bf16x8*)&qrow[c * 8];
      *(bf16x8*)&Ks[l * 32 + c * 8] = *(const bf16x8*)&qrow[384 + c * 8];
    }
#pragma unroll
    for (int c = 0; c < 4; c++) {
      bf16x8 tv = *(const bf16x8*)&qrow[768 + c * 8];
#pragma unroll
      for (int e = 0; e < 8; e++) {
        int vr = c * 8 + e;
        Vt[vr * 64 + (l ^ ((vr & 7) << 3))] = tv[e];  // swizzled col
      }
    }
  }
  __syncthreads();

  // S = Q K^T  (64x64, K=32); Q pre-scaled via weight fold
  f32x4 sacc[4][4] = {};
  {
    bf16x8 a[4], b[4];
#pragma unroll
    for (int fi = 0; fi < 4; fi++)
      a[fi] = *(const bf16x8*)&Qs[(fi * 16 + lr) * 32 + lq * 8];
#pragma unroll
    for (int fj = 0; fj < 4; fj++)
      b[fj] = *(const bf16x8*)&Ks[(fj * 16 + lr) * 32 + lq * 8];
#pragma unroll
    for (int fi = 0; fi < 4; fi++)
#pragma unroll
      for (int fj = 0; fj < 4; fj++)
        sacc[fi][fj] = mfma16(a[fi], b[fj], sacc[fi][fj]);
  }

  // softmax with precomputed bias+mask table (coalesced 64B row-segment loads)
  const int widx = win & 63;
  const int cls = (((widx >> 3) == 7) << 1) | ((widx & 7) == 7);
  const float* bfp = biasF + (((size_t)cls * 12 + h) << 12);
#pragma unroll
  for (int fi = 0; fi < 4; fi++) {
#pragma unroll
    for (int reg = 0; reg < 4; reg++) {
      int row = fi * 16 + lq * 4 + reg;  // C/D: row=(l>>4)*4+reg (+fi*16)
      const float* brow = bfp + row * 64 + lr;
      float vals[4], m = -1e30f;
#pragma unroll
      for (int fj = 0; fj < 4; fj++) {
        float v = sacc[fi][fj][reg] + brow[fj * 16];
        vals[fj] = v;
        m = fmaxf(m, v);
      }
#pragma unroll
      for (int o = 1; o < 16; o <<= 1) m = fmaxf(m, __shfl_xor(m, o));
      float ssum = 0.f;
#pragma unroll
      for (int fj = 0; fj < 4; fj++) {
        vals[fj] = __expf(vals[fj] - m);
        ssum += vals[fj];
      }
#pragma unroll
      for (int o = 1; o < 16; o <<= 1) ssum += __shfl_xor(ssum, o);
      float inv = 1.f / ssum;
      int sw = (row & 7) << 3;
#pragma unroll
      for (int fj = 0; fj < 4; fj++)
        Ps[row * 64 + ((fj * 16 + lr) ^ sw)] = (bf16_t)(vals[fj] * inv);
    }
  }
  __syncthreads();

  // O = P V  (64x32, K=64); swizzled Ps / Vt reads (conflict-free)
  f32x4 oacc[4][2] = {};
#pragma unroll
  for (int kc = 0; kc < 2; kc++) {
    bf16x8 pa[4], vb[2];
#pragma unroll
    for (int fi = 0; fi < 4; fi++) {
      int row = fi * 16 + lr;
      pa[fi] = *(const bf16x8*)&Ps[row * 64 + ((kc * 32 + lq * 8) ^ ((row & 7) << 3))];
    }
#pragma unroll
    for (int fj = 0; fj < 2; fj++) {
      int row = fj * 16 + lr;
      vb[fj] = *(const bf16x8*)&Vt[row * 64 + ((kc * 32 + lq * 8) ^ ((row & 7) << 3))];
    }
#pragma unroll
    for (int fi = 0; fi < 4; fi++)
#pragma unroll
      for (int fj = 0; fj < 2; fj++)
        oacc[fi][fj] = mfma16(pa[fi], vb[fj], oacc[fi][fj]);
  }
#pragma unroll
  for (int fi = 0; fi < 4; fi++)
#pragma unroll
    for (int reg = 0; reg < 4; reg++) {
      int row = fi * 16 + lq * 4 + reg;
      size_t rb = ((size_t)win * 64 + row) * 384 + h * 32;
#pragma unroll
      for (int fj = 0; fj < 2; fj++)
        aout[rb + fj * 16 + lr] = (bf16_t)oacc[fi][fj][reg];
    }
}

// ---------------------------------------------------------------------------
extern "C" void kernel_launch(void* const* d_in, const int* in_sizes, int n_in,
                              void* d_out, int out_size, void* d_ws, size_t ws_size,
                              hipStream_t stream) {
  (void)in_sizes; (void)n_in; (void)out_size; (void)ws_size;
  const float* x      = (const float*)d_in[0];
  const float* gamma1 = (const float*)d_in[1];
  const float* beta1  = (const float*)d_in[2];
  const float* w_qkv  = (const float*)d_in[3];
  const float* b_qkv  = (const float*)d_in[4];
  const float* btab   = (const float*)d_in[5];
  const float* w_proj = (const float*)d_in[6];
  const float* b_proj = (const float*)d_in[7];
  const float* gamma2 = (const float*)d_in[8];
  const float* beta2  = (const float*)d_in[9];
  const float* w_fc1  = (const float*)d_in[10];
  const float* b_fc1  = (const float*)d_in[11];
  const float* w_fc2  = (const float*)d_in[12];
  const float* b_fc2  = (const float*)d_in[13];
  float* out = (float*)d_out;

  char* ws = (char*)d_ws;
  size_t off = 0;
  auto alloc = [&](size_t bytes) {
    void* p = ws + off;
    off += (bytes + 255) & ~(size_t)255;
    return p;
  };
  bf16_t* wqkvT  = (bf16_t*)alloc((size_t)1152 * 384 * 2);
  bf16_t* wprojT = (bf16_t*)alloc((size_t)384 * 384 * 2);
  bf16_t* wfc1T  = (bf16_t*)alloc((size_t)1536 * 384 * 2);
  bf16_t* wfc2T  = (bf16_t*)alloc((size_t)384 * 1536 * 2);
  float*  bqs    = (float*)alloc((size_t)1152 * 4);
  float*  biasF  = (float*)alloc((size_t)4 * 12 * 4096 * 4);
  // qkv rows [TOK][1152] alias mlp hidden [TOK][1536]; lifetimes disjoint.
  char* big = (char*)alloc((size_t)TOK * 1536 * 2);
  bf16_t* bufA = (bf16_t*)big;  // qkv rows
  bf16_t* bufH = (bf16_t*)big;  // mlp hidden
  bf16_t* bufB = (bf16_t*)alloc((size_t)TOK * 384 * 2);  // ln1/attn/ln2 rows

  // merged weight conversion (+Q-scale fold) and bias table build
  wconv_all<<<(1769472 + 1152 + 255) / 256, 256, 0, stream>>>(
      w_qkv, w_proj, w_fc1, w_fc2, b_qkv, wqkvT, wprojT, wfc1T, wfc2T, bqs);
  bias_build<<<(4 * 12 * 4096) / 256, 256, 0, stream>>>(btab, biasF);

  // LN1 + roll + window partition -> bufB [131072][384] bf16
  ln_kernel<1><<<TOK / 4, 256, 0, stream>>>(x, gamma1, beta1, bufB);
  // QKV: [131072,384] x [384,1152] -> bufA bf16   (grid 9*512, %8==0)
  gemm_bt<0><<<9 * (TOK / 256), 256, 0, stream>>>(
      bufB, wqkvT, bqs, 384, 1152, 9, bufA, nullptr, nullptr);
  // windowed attention -> bufB [131072][384] bf16
  attn_kernel<<<dim3(NWIN, 12), 64, 0, stream>>>(bufA, biasF, bufB);
  // proj + un-roll scatter + residual(x) -> out (x1, f32)  (grid 3*512)
  gemm_bt<2><<<3 * (TOK / 256), 256, 0, stream>>>(
      bufB, wprojT, b_proj, 384, 384, 3, nullptr, out, x);
  // LN2 -> bufB bf16
  ln_kernel<0><<<TOK / 4, 256, 0, stream>>>(out, gamma2, beta2, bufB);
  // FC1 + fast GELU -> bufH [131072][1536] bf16  (grid 12*512)
  gemm_bt<1><<<12 * (TOK / 256), 256, 0, stream>>>(
      bufB, wfc1T, b_fc1, 384, 1536, 12, bufH, nullptr, nullptr);
  // FC2 + residual(out, in-place) -> out  (grid 3*512)
  gemm_bt<3><<<3 * (TOK / 256), 256, 0, stream>>>(
      bufH, wfc2T, b_fc2, 1536, 384, 3, nullptr, out, out);
}

// Round 15
// 1177.773 us; speedup vs baseline: 1.1028x; 1.1028x over previous
//
#include <hip/hip_runtime.h>
#include <hip/hip_bf16.h>

typedef __bf16 bf16_t;
typedef __bf16 bf16x8 __attribute__((ext_vector_type(8)));
typedef float f32x4 __attribute__((ext_vector_type(4)));

#define DI __device__ __forceinline__

static constexpr int TOK = 131072;  // 32 batches * 64*64 tokens
static constexpr int NWIN = 2048;   // 32 * 64 windows

// window-order token t -> source image token (LN1 gather) == proj scatter dest.
DI int src_token(int t) {
  int b = t >> 12;
  int widx = (t >> 6) & 63;
  int n = t & 63;
  int wh = widx >> 3, ww = widx & 7;
  int i = n >> 3, j = n & 7;
  int y = ((wh << 3) + i + 4) & 63;
  int x2 = ((ww << 3) + j + 4) & 63;
  return (b << 12) + (y << 6) + x2;
}

DI f32x4 mfma16(bf16x8 a, bf16x8 b, f32x4 c) {
  return __builtin_amdgcn_mfma_f32_16x16x32_bf16(a, b, c, 0, 0, 0);
}

DI void gload_lds16(const bf16_t* g, bf16_t* l) {
  __builtin_amdgcn_global_load_lds(
      (__attribute__((address_space(1))) void*)const_cast<bf16_t*>(g),
      (__attribute__((address_space(3))) void*)l, 16, 0, 0);
}

// ------ merged prep: weight transpose+convert (+Q-scale fold) + scaled b_qkv
//        + bias_full table, all in ONE launch ------
__global__ void prep_all(const float* __restrict__ wq, const float* __restrict__ wp,
                         const float* __restrict__ w1, const float* __restrict__ w2,
                         const float* __restrict__ bq, const float* __restrict__ btab,
                         bf16_t* oq, bf16_t* op_, bf16_t* o1, bf16_t* o2,
                         float* bqs, float* bf) {
  int idx = blockIdx.x * 256 + threadIdx.x;
  const float s = 0.17677669529663687f;  // 32^-0.5
  if (idx < 442368) {
    int n = idx / 384, k = idx - n * 384;
    float v = wq[(size_t)k * 1152 + n];
    if (n < 384) v *= s;
    oq[idx] = (bf16_t)v;
  } else if ((idx -= 442368) < 147456) {
    int n = idx / 384, k = idx - n * 384;
    op_[idx] = (bf16_t)wp[(size_t)k * 384 + n];
  } else if ((idx -= 147456) < 589824) {
    int n = idx / 384, k = idx - n * 384;
    o1[idx] = (bf16_t)w1[(size_t)k * 1536 + n];
  } else if ((idx -= 589824) < 589824) {
    int n = idx / 1536, k = idx - n * 1536;
    o2[idx] = (bf16_t)w2[(size_t)k * 384 + n];
  } else if ((idx -= 589824) < 1152) {
    bqs[idx] = bq[idx] * (idx < 384 ? s : 1.f);
  } else if ((idx -= 1152) < 4 * 12 * 4096) {
    // bias_full[4 classes][12 heads][64][64] = rel_bias + shift-mask
    int c = idx & 63, r = (idx >> 6) & 63;
    int hh = idx >> 12;
    int h = hh % 12, cls = hh / 12;
    int i1 = r >> 3, j1 = r & 7, i2 = c >> 3, j2 = c & 7;
    float v = btab[((i1 - i2 + 7) * 15 + (j1 - j2 + 7)) * 12 + h];
    int wh7 = cls >> 1, ww7 = cls & 1;
    int ly1 = wh7 ? (i1 >= 4 ? 2 : 1) : 0;
    int ly2 = wh7 ? (i2 >= 4 ? 2 : 1) : 0;
    int lx1 = ww7 ? (j1 >= 4 ? 2 : 1) : 0;
    int lx2 = ww7 ? (j2 >= 4 ? 2 : 1) : 0;
    if (ly1 != ly2 || lx1 != lx2) v -= 100.f;
    bf[idx] = v;
  }
}

// ---------------- LayerNorm (+optional shift/partition gather), f32 -> bf16 --
template <int MAP>
__global__ __launch_bounds__(256)
void ln_kernel(const float* __restrict__ xin, const float* __restrict__ g,
               const float* __restrict__ be, bf16_t* __restrict__ out) {
  int w = threadIdx.x >> 6, l = threadIdx.x & 63;
  int t = blockIdx.x * 4 + w;
  int s = MAP ? src_token(t) : t;
  const float* row = xin + (size_t)s * 384;
  float v[6], s1 = 0.f, s2 = 0.f;
#pragma unroll
  for (int i = 0; i < 6; i++) {
    v[i] = row[l + i * 64];
    s1 += v[i];
    s2 += v[i] * v[i];
  }
#pragma unroll
  for (int o = 32; o; o >>= 1) {
    s1 += __shfl_xor(s1, o);
    s2 += __shfl_xor(s2, o);
  }
  float mean = s1 * (1.f / 384.f);
  float var = s2 * (1.f / 384.f) - mean * mean;
  float rs = rsqrtf(var + 1e-5f);
  bf16_t* orow = out + (size_t)t * 384;
#pragma unroll
  for (int i = 0; i < 6; i++) {
    int idx = l + i * 64;
    orow[idx] = (bf16_t)((v[i] - mean) * rs * g[idx] + be[idx]);
  }
}

// ---------------- GEMM: C[M][N] = A[M][K]*Wt[N][K]^T + bias ------------------
// r13-proven kernel FROZEN: single-buffered 32KB LDS, BK=64, 2 barriers per
// K-tile, both-sides XOR swizzle, XCD-chunked remap, VALU diet. Structure law
// (5 experiments): GEMM time tracks blocks/CU at these shapes; 4/CU ~ 300us.
// MODE 0: bf16 out. 1: bf16 gelu(out). 2: f32 scatter(src_token)+resid.
// MODE 3: f32 +resid (resid aliases outf; element owned by one thread).
template <int MODE>
__global__ __launch_bounds__(256, 4)
void gemm_bt(const bf16_t* __restrict__ A, const bf16_t* __restrict__ Wt,
             const float* __restrict__ bias, int K, int ldout, int ncols,
             bf16_t* outb, float* outf, const float* resid) {
  __shared__ __align__(16) bf16_t Alds[128 * 64];
  __shared__ __align__(16) bf16_t Blds[128 * 64];
  const int tid = threadIdx.x;
  const int l = tid & 63, w = tid >> 6;
  const int lr = l & 15, lq = l >> 4;
  const int nwg = gridDim.x;
  const int orig = blockIdx.x;
  const int wgid = (orig & 7) * (nwg >> 3) + (orig >> 3);
  const int bn = wgid % ncols, bm = wgid / ncols;
  const int wr = w >> 1, wc = w & 1;

  const int srow = w * 8 + (l >> 3);
  const int scol = ((l & 7) ^ (l >> 3)) << 3;
  const bf16_t* ga = A + ((size_t)bm * 128 + srow) * K + scol;
  const bf16_t* gb = Wt + ((size_t)bn * 128 + srow) * K + scol;
  const size_t k32 = (size_t)32 * K;
  bf16_t* la = &Alds[w * 512];
  bf16_t* lb = &Blds[w * 512];

  int aoff[8], boff[8];
#pragma unroll
  for (int fi = 0; fi < 4; fi++) {
    int ra = wr * 64 + fi * 16 + lr;
    int rb = wc * 64 + fi * 16 + lr;
#pragma unroll
    for (int ks = 0; ks < 2; ks++) {
      aoff[fi * 2 + ks] = ra * 64 + ((ks * 32 + lq * 8) ^ ((ra & 7) << 3));
      boff[fi * 2 + ks] = rb * 64 + ((ks * 32 + lq * 8) ^ ((rb & 7) << 3));
    }
  }

  f32x4 acc[4][4] = {};
  const int nt = K >> 6;
  for (int t = 0; t < nt; t++) {
#pragma unroll
    for (int r = 0; r < 4; r++) {
      gload_lds16(ga + r * k32, la + r * 2048);
      gload_lds16(gb + r * k32, lb + r * 2048);
    }
    ga += 64;
    gb += 64;
    __syncthreads();
#pragma unroll
    for (int ks = 0; ks < 2; ks++) {
      bf16x8 af[4], bfr[4];
#pragma unroll
      for (int fi = 0; fi < 4; fi++)
        af[fi] = *(const bf16x8*)&Alds[aoff[fi * 2 + ks]];
#pragma unroll
      for (int fj = 0; fj < 4; fj++)
        bfr[fj] = *(const bf16x8*)&Blds[boff[fj * 2 + ks]];
#pragma unroll
      for (int fi = 0; fi < 4; fi++)
#pragma unroll
        for (int fj = 0; fj < 4; fj++)
          acc[fi][fj] = mfma16(af[fi], bfr[fj], acc[fi][fj]);
    }
    __syncthreads();
  }

  float bv[4];
#pragma unroll
  for (int fj = 0; fj < 4; fj++)
    bv[fj] = bias[bn * 128 + wc * 64 + fj * 16 + lr];
#pragma unroll
  for (int fi = 0; fi < 4; fi++) {
#pragma unroll
    for (int reg = 0; reg < 4; reg++) {
      int grow = bm * 128 + wr * 64 + fi * 16 + lq * 4 + reg;
      size_t rbase;
      if constexpr (MODE == 2)
        rbase = (size_t)src_token(grow) * ldout;
      else
        rbase = (size_t)grow * ldout;
#pragma unroll
      for (int fj = 0; fj < 4; fj++) {
        int gcol = bn * 128 + wc * 64 + fj * 16 + lr;
        float val = acc[fi][fj][reg] + bv[fj];
        if constexpr (MODE == 0) {
          outb[rbase + gcol] = (bf16_t)val;
        } else if constexpr (MODE == 1) {
          // tanh-form GELU via fast sigmoid (rcp instead of div)
          float z = -1.5957691216f * val * fmaf(0.044715f, val * val, 1.0f);
          val = val * __builtin_amdgcn_rcpf(1.0f + __expf(z));
          outb[rbase + gcol] = (bf16_t)val;
        } else {
          outf[rbase + gcol] = val + resid[rbase + gcol];
        }
      }
    }
  }
}

// ---------------- per-(window, head) attention ------------------------------
// h-fastest grid: the 12 head-blocks of one window are dispatch-adjacent so
// the window's 147KB of qkv rows is fetched once (was: 12 full-buffer sweeps).
// Q/K fragments load DIRECTLY from global (each is a contiguous aligned 16B
// chunk; verified correct r12) — no LDS round trip, no first barrier (1-wave
// block: the pre-PV barrier's lgkmcnt(0) orders the Vt writes). LDS 12KB ->
// 13 blocks/CU residency (was 8). Bias+mask via precomputed table (r13).
__global__ __launch_bounds__(64)
void attn_kernel(const bf16_t* __restrict__ qkv, const float* __restrict__ biasF,
                 bf16_t* __restrict__ aout) {
  __shared__ __align__(16) bf16_t Vt[32 * 64];
  __shared__ __align__(16) bf16_t Ps[64 * 64];
  const int h = blockIdx.x, win = blockIdx.y;  // h fastest
  const int l = threadIdx.x, lr = l & 15, lq = l >> 4;
  const bf16_t* qbase = qkv + (size_t)win * 64 * 1152 + h * 32;

  // stage V transposed (swizzled cols); visibility ensured by pre-PV barrier
  {
    const bf16_t* vrow = qbase + l * 1152 + 768;
#pragma unroll
    for (int c = 0; c < 4; c++) {
      bf16x8 tv = *(const bf16x8*)&vrow[c * 8];
#pragma unroll
      for (int e = 0; e < 8; e++) {
        int vr = c * 8 + e;
        Vt[vr * 64 + (l ^ ((vr & 7) << 3))] = tv[e];
      }
    }
  }

  // S = Q K^T  (64x64, K=32); Q pre-scaled via weight fold; direct loads
  f32x4 sacc[4][4] = {};
  {
    bf16x8 a[4], b[4];
#pragma unroll
    for (int fi = 0; fi < 4; fi++)
      a[fi] = *(const bf16x8*)(qbase + (size_t)(fi * 16 + lr) * 1152 + lq * 8);
#pragma unroll
    for (int fj = 0; fj < 4; fj++)
      b[fj] = *(const bf16x8*)(qbase + 384 + (size_t)(fj * 16 + lr) * 1152 + lq * 8);
#pragma unroll
    for (int fi = 0; fi < 4; fi++)
#pragma unroll
      for (int fj = 0; fj < 4; fj++)
        sacc[fi][fj] = mfma16(a[fi], b[fj], sacc[fi][fj]);
  }

  // softmax with precomputed bias+mask table (coalesced row-segment loads)
  const int widx = win & 63;
  const int cls = (((widx >> 3) == 7) << 1) | ((widx & 7) == 7);
  const float* bfp = biasF + (((size_t)cls * 12 + h) << 12);
#pragma unroll
  for (int fi = 0; fi < 4; fi++) {
#pragma unroll
    for (int reg = 0; reg < 4; reg++) {
      int row = fi * 16 + lq * 4 + reg;  // C/D: row=(l>>4)*4+reg (+fi*16)
      const float* brow = bfp + row * 64 + lr;
      float vals[4], m = -1e30f;
#pragma unroll
      for (int fj = 0; fj < 4; fj++) {
        float v = sacc[fi][fj][reg] + brow[fj * 16];
        vals[fj] = v;
        m = fmaxf(m, v);
      }
#pragma unroll
      for (int o = 1; o < 16; o <<= 1) m = fmaxf(m, __shfl_xor(m, o));
      float ssum = 0.f;
#pragma unroll
      for (int fj = 0; fj < 4; fj++) {
        vals[fj] = __expf(vals[fj] - m);
        ssum += vals[fj];
      }
#pragma unroll
      for (int o = 1; o < 16; o <<= 1) ssum += __shfl_xor(ssum, o);
      float inv = 1.f / ssum;
      int sw = (row & 7) << 3;
#pragma unroll
      for (int fj = 0; fj < 4; fj++)
        Ps[row * 64 + ((fj * 16 + lr) ^ sw)] = (bf16_t)(vals[fj] * inv);
    }
  }
  __syncthreads();  // orders Vt + Ps writes before the reads below

  // O = P V  (64x32, K=64); swizzled Ps / Vt reads (conflict-free)
  f32x4 oacc[4][2] = {};
#pragma unroll
  for (int kc = 0; kc < 2; kc++) {
    bf16x8 pa[4], vb[2];
#pragma unroll
    for (int fi = 0; fi < 4; fi++) {
      int row = fi * 16 + lr;
      pa[fi] = *(const bf16x8*)&Ps[row * 64 + ((kc * 32 + lq * 8) ^ ((row & 7) << 3))];
    }
#pragma unroll
    for (int fj = 0; fj < 2; fj++) {
      int row = fj * 16 + lr;
      vb[fj] = *(const bf16x8*)&Vt[row * 64 + ((kc * 32 + lq * 8) ^ ((row & 7) << 3))];
    }
#pragma unroll
    for (int fi = 0; fi < 4; fi++)
#pragma unroll
      for (int fj = 0; fj < 2; fj++)
        oacc[fi][fj] = mfma16(pa[fi], vb[fj], oacc[fi][fj]);
  }
#pragma unroll
  for (int fi = 0; fi < 4; fi++)
#pragma unroll
    for (int reg = 0; reg < 4; reg++) {
      int row = fi * 16 + lq * 4 + reg;
      size_t rb = ((size_t)win * 64 + row) * 384 + h * 32;
#pragma unroll
      for (int fj = 0; fj < 2; fj++)
        aout[rb + fj * 16 + lr] = (bf16_t)oacc[fi][fj][reg];
    }
}

// ---------------------------------------------------------------------------
extern "C" void kernel_launch(void* const* d_in, const int* in_sizes, int n_in,
                              void* d_out, int out_size, void* d_ws, size_t ws_size,
                              hipStream_t stream) {
  (void)in_sizes; (void)n_in; (void)out_size; (void)ws_size;
  const float* x      = (const float*)d_in[0];
  const float* gamma1 = (const float*)d_in[1];
  const float* beta1  = (const float*)d_in[2];
  const float* w_qkv  = (const float*)d_in[3];
  const float* b_qkv  = (const float*)d_in[4];
  const float* btab   = (const float*)d_in[5];
  const float* w_proj = (const float*)d_in[6];
  const float* b_proj = (const float*)d_in[7];
  const float* gamma2 = (const float*)d_in[8];
  const float* beta2  = (const float*)d_in[9];
  const float* w_fc1  = (const float*)d_in[10];
  const float* b_fc1  = (const float*)d_in[11];
  const float* w_fc2  = (const float*)d_in[12];
  const float* b_fc2  = (const float*)d_in[13];
  float* out = (float*)d_out;

  char* ws = (char*)d_ws;
  size_t off = 0;
  auto alloc = [&](size_t bytes) {
    void* p = ws + off;
    off += (bytes + 255) & ~(size_t)255;
    return p;
  };
  bf16_t* wqkvT  = (bf16_t*)alloc((size_t)1152 * 384 * 2);
  bf16_t* wprojT = (bf16_t*)alloc((size_t)384 * 384 * 2);
  bf16_t* wfc1T  = (bf16_t*)alloc((size_t)1536 * 384 * 2);
  bf16_t* wfc2T  = (bf16_t*)alloc((size_t)384 * 1536 * 2);
  float*  bqs    = (float*)alloc((size_t)1152 * 4);
  float*  biasF  = (float*)alloc((size_t)4 * 12 * 4096 * 4);
  // qkv rows [TOK][1152] alias mlp hidden [TOK][1536]; lifetimes disjoint.
  char* big = (char*)alloc((size_t)TOK * 1536 * 2);
  bf16_t* bufA = (bf16_t*)big;  // qkv rows
  bf16_t* bufH = (bf16_t*)big;  // mlp hidden
  bf16_t* bufB = (bf16_t*)alloc((size_t)TOK * 384 * 2);  // ln1/attn/ln2 rows

  // merged prep: weight conversion (+Q-scale fold), scaled b_qkv, bias table
  prep_all<<<(1769472 + 1152 + 196608 + 255) / 256, 256, 0, stream>>>(
      w_qkv, w_proj, w_fc1, w_fc2, b_qkv, btab,
      wqkvT, wprojT, wfc1T, wfc2T, bqs, biasF);

  // LN1 + roll + window partition -> bufB [131072][384] bf16
  ln_kernel<1><<<TOK / 4, 256, 0, stream>>>(x, gamma1, beta1, bufB);
  // QKV: [131072,384] x [384,1152] -> bufA bf16   (grid 9*1024, %8==0)
  gemm_bt<0><<<9 * (TOK / 128), 256, 0, stream>>>(
      bufB, wqkvT, bqs, 384, 1152, 9, bufA, nullptr, nullptr);
  // windowed attention -> bufB [131072][384] bf16  (h fastest)
  attn_kernel<<<dim3(12, NWIN), 64, 0, stream>>>(bufA, biasF, bufB);
  // proj + un-roll scatter + residual(x) -> out (x1, f32)  (grid 3*1024)
  gemm_bt<2><<<3 * (TOK / 128), 256, 0, stream>>>(
      bufB, wprojT, b_proj, 384, 384, 3, nullptr, out, x);
  // LN2 -> bufB bf16
  ln_kernel<0><<<TOK / 4, 256, 0, stream>>>(out, gamma2, beta2, bufB);
  // FC1 + fast GELU -> bufH [131072][1536] bf16  (grid 12*1024)
  gemm_bt<1><<<12 * (TOK / 128), 256, 0, stream>>>(
      bufB, wfc1T, b_fc1, 384, 1536, 12, bufH, nullptr, nullptr);
  // FC2 + residual(out, in-place) -> out  (grid 3*1024)
  gemm_bt<3><<<3 * (TOK / 128), 256, 0, stream>>>(
      bufH, wfc2T, b_fc2, 1536, 384, 3, nullptr, out, out);
}

// Round 16
// 1137.457 us; speedup vs baseline: 1.1419x; 1.0354x over previous
//
#include <hip/hip_runtime.h>
#include <hip/hip_bf16.h>

typedef __bf16 bf16_t;
typedef __bf16 bf16x8 __attribute__((ext_vector_type(8)));
typedef float f32x4 __attribute__((ext_vector_type(4)));

#define DI __device__ __forceinline__

static constexpr int TOK = 131072;  // 32 batches * 64*64 tokens
static constexpr int NWIN = 2048;   // 32 * 64 windows

// window-order token t -> source image token (LN1 gather) == proj scatter dest.
DI int src_token(int t) {
  int b = t >> 12;
  int widx = (t >> 6) & 63;
  int n = t & 63;
  int wh = widx >> 3, ww = widx & 7;
  int i = n >> 3, j = n & 7;
  int y = ((wh << 3) + i + 4) & 63;
  int x2 = ((ww << 3) + j + 4) & 63;
  return (b << 12) + (y << 6) + x2;
}

DI f32x4 mfma16(bf16x8 a, bf16x8 b, f32x4 c) {
  return __builtin_amdgcn_mfma_f32_16x16x32_bf16(a, b, c, 0, 0, 0);
}

DI void gload_lds16(const bf16_t* g, bf16_t* l) {
  __builtin_amdgcn_global_load_lds(
      (__attribute__((address_space(1))) void*)const_cast<bf16_t*>(g),
      (__attribute__((address_space(3))) void*)l, 16, 0, 0);
}

// ------ merged prep: weight transpose+convert (+Q-scale fold) + scaled b_qkv
//        + bias_full table (bf16), all in ONE launch ------
__global__ void prep_all(const float* __restrict__ wq, const float* __restrict__ wp,
                         const float* __restrict__ w1, const float* __restrict__ w2,
                         const float* __restrict__ bq, const float* __restrict__ btab,
                         bf16_t* oq, bf16_t* op_, bf16_t* o1, bf16_t* o2,
                         float* bqs, bf16_t* bf) {
  int idx = blockIdx.x * 256 + threadIdx.x;
  const float s = 0.17677669529663687f;  // 32^-0.5
  if (idx < 442368) {
    int n = idx / 384, k = idx - n * 384;
    float v = wq[(size_t)k * 1152 + n];
    if (n < 384) v *= s;
    oq[idx] = (bf16_t)v;
  } else if ((idx -= 442368) < 147456) {
    int n = idx / 384, k = idx - n * 384;
    op_[idx] = (bf16_t)wp[(size_t)k * 384 + n];
  } else if ((idx -= 147456) < 589824) {
    int n = idx / 384, k = idx - n * 384;
    o1[idx] = (bf16_t)w1[(size_t)k * 1536 + n];
  } else if ((idx -= 589824) < 589824) {
    int n = idx / 1536, k = idx - n * 1536;
    o2[idx] = (bf16_t)w2[(size_t)k * 384 + n];
  } else if ((idx -= 589824) < 1152) {
    bqs[idx] = bq[idx] * (idx < 384 ? s : 1.f);
  } else if ((idx -= 1152) < 4 * 12 * 4096) {
    // bias_full[4 classes][12 heads][64][64] = rel_bias + shift-mask, bf16.
    // |rel_bias|~0.1 (abs err ~2e-4 in bf16); -100 mask exact to 0.5 ulp —
    // both negligible vs the 0.114 output threshold.
    int c = idx & 63, r = (idx >> 6) & 63;
    int hh = idx >> 12;
    int h = hh % 12, cls = hh / 12;
    int i1 = r >> 3, j1 = r & 7, i2 = c >> 3, j2 = c & 7;
    float v = btab[((i1 - i2 + 7) * 15 + (j1 - j2 + 7)) * 12 + h];
    int wh7 = cls >> 1, ww7 = cls & 1;
    int ly1 = wh7 ? (i1 >= 4 ? 2 : 1) : 0;
    int ly2 = wh7 ? (i2 >= 4 ? 2 : 1) : 0;
    int lx1 = ww7 ? (j1 >= 4 ? 2 : 1) : 0;
    int lx2 = ww7 ? (j2 >= 4 ? 2 : 1) : 0;
    if (ly1 != ly2 || lx1 != lx2) v -= 100.f;
    bf[idx] = (bf16_t)v;
  }
}

// ---------------- LayerNorm (+optional shift/partition gather), f32 -> bf16 --
template <int MAP>
__global__ __launch_bounds__(256)
void ln_kernel(const float* __restrict__ xin, const float* __restrict__ g,
               const float* __restrict__ be, bf16_t* __restrict__ out) {
  int w = threadIdx.x >> 6, l = threadIdx.x & 63;
  int t = blockIdx.x * 4 + w;
  int s = MAP ? src_token(t) : t;
  const float* row = xin + (size_t)s * 384;
  float v[6], s1 = 0.f, s2 = 0.f;
#pragma unroll
  for (int i = 0; i < 6; i++) {
    v[i] = row[l + i * 64];
    s1 += v[i];
    s2 += v[i] * v[i];
  }
#pragma unroll
  for (int o = 32; o; o >>= 1) {
    s1 += __shfl_xor(s1, o);
    s2 += __shfl_xor(s2, o);
  }
  float mean = s1 * (1.f / 384.f);
  float var = s2 * (1.f / 384.f) - mean * mean;
  float rs = rsqrtf(var + 1e-5f);
  bf16_t* orow = out + (size_t)t * 384;
#pragma unroll
  for (int i = 0; i < 6; i++) {
    int idx = l + i * 64;
    orow[idx] = (bf16_t)((v[i] - mean) * rs * g[idx] + be[idx]);
  }
}

// ---------------- GEMM: C[M][N] = A[M][K]*Wt[N][K]^T + bias ------------------
// r13-proven kernel FROZEN: single-buffered 32KB LDS, BK=64, 2 barriers per
// K-tile, both-sides XOR swizzle, XCD-chunked remap, VALU diet. Structure law
// (6 experiments): GEMM time tracks blocks/CU at these shapes; 4/CU ~ 300us.
// MODE 0: bf16 out. 1: bf16 gelu(out). 2: f32 scatter(src_token)+resid.
// MODE 3: f32 +resid (resid aliases outf; element owned by one thread).
template <int MODE>
__global__ __launch_bounds__(256, 4)
void gemm_bt(const bf16_t* __restrict__ A, const bf16_t* __restrict__ Wt,
             const float* __restrict__ bias, int K, int ldout, int ncols,
             bf16_t* outb, float* outf, const float* resid) {
  __shared__ __align__(16) bf16_t Alds[128 * 64];
  __shared__ __align__(16) bf16_t Blds[128 * 64];
  const int tid = threadIdx.x;
  const int l = tid & 63, w = tid >> 6;
  const int lr = l & 15, lq = l >> 4;
  const int nwg = gridDim.x;
  const int orig = blockIdx.x;
  const int wgid = (orig & 7) * (nwg >> 3) + (orig >> 3);
  const int bn = wgid % ncols, bm = wgid / ncols;
  const int wr = w >> 1, wc = w & 1;

  const int srow = w * 8 + (l >> 3);
  const int scol = ((l & 7) ^ (l >> 3)) << 3;
  const bf16_t* ga = A + ((size_t)bm * 128 + srow) * K + scol;
  const bf16_t* gb = Wt + ((size_t)bn * 128 + srow) * K + scol;
  const size_t k32 = (size_t)32 * K;
  bf16_t* la = &Alds[w * 512];
  bf16_t* lb = &Blds[w * 512];

  int aoff[8], boff[8];
#pragma unroll
  for (int fi = 0; fi < 4; fi++) {
    int ra = wr * 64 + fi * 16 + lr;
    int rb = wc * 64 + fi * 16 + lr;
#pragma unroll
    for (int ks = 0; ks < 2; ks++) {
      aoff[fi * 2 + ks] = ra * 64 + ((ks * 32 + lq * 8) ^ ((ra & 7) << 3));
      boff[fi * 2 + ks] = rb * 64 + ((ks * 32 + lq * 8) ^ ((rb & 7) << 3));
    }
  }

  f32x4 acc[4][4] = {};
  const int nt = K >> 6;
  for (int t = 0; t < nt; t++) {
#pragma unroll
    for (int r = 0; r < 4; r++) {
      gload_lds16(ga + r * k32, la + r * 2048);
      gload_lds16(gb + r * k32, lb + r * 2048);
    }
    ga += 64;
    gb += 64;
    __syncthreads();
#pragma unroll
    for (int ks = 0; ks < 2; ks++) {
      bf16x8 af[4], bfr[4];
#pragma unroll
      for (int fi = 0; fi < 4; fi++)
        af[fi] = *(const bf16x8*)&Alds[aoff[fi * 2 + ks]];
#pragma unroll
      for (int fj = 0; fj < 4; fj++)
        bfr[fj] = *(const bf16x8*)&Blds[boff[fj * 2 + ks]];
#pragma unroll
      for (int fi = 0; fi < 4; fi++)
#pragma unroll
        for (int fj = 0; fj < 4; fj++)
          acc[fi][fj] = mfma16(af[fi], bfr[fj], acc[fi][fj]);
    }
    __syncthreads();
  }

  float bv[4];
#pragma unroll
  for (int fj = 0; fj < 4; fj++)
    bv[fj] = bias[bn * 128 + wc * 64 + fj * 16 + lr];
#pragma unroll
  for (int fi = 0; fi < 4; fi++) {
#pragma unroll
    for (int reg = 0; reg < 4; reg++) {
      int grow = bm * 128 + wr * 64 + fi * 16 + lq * 4 + reg;
      size_t rbase;
      if constexpr (MODE == 2)
        rbase = (size_t)src_token(grow) * ldout;
      else
        rbase = (size_t)grow * ldout;
#pragma unroll
      for (int fj = 0; fj < 4; fj++) {
        int gcol = bn * 128 + wc * 64 + fj * 16 + lr;
        float val = acc[fi][fj][reg] + bv[fj];
        if constexpr (MODE == 0) {
          outb[rbase + gcol] = (bf16_t)val;
        } else if constexpr (MODE == 1) {
          // tanh-form GELU via fast sigmoid (rcp instead of div)
          float z = -1.5957691216f * val * fmaf(0.044715f, val * val, 1.0f);
          val = val * __builtin_amdgcn_rcpf(1.0f + __expf(z));
          outb[rbase + gcol] = (bf16_t)val;
        } else {
          outf[rbase + gcol] = val + resid[rbase + gcol];
        }
      }
    }
  }
}

// ---------------- per-(window, head) attention ------------------------------
// r15 structure + (a) bf16 bias table (halves the 402MB table flow — the
// largest byte stream in this cache-BW-bound kernel) and (b) T5 s_setprio(1)
// around MFMA clusters (catalog m191: +4-7% on exactly this regime —
// independent 1-wave blocks phase-staggered on a CU; null only on lockstep
// GEMM, so applied here only).
__global__ __launch_bounds__(64)
void attn_kernel(const bf16_t* __restrict__ qkv, const bf16_t* __restrict__ biasF,
                 bf16_t* __restrict__ aout) {
  __shared__ __align__(16) bf16_t Vt[32 * 64];
  __shared__ __align__(16) bf16_t Ps[64 * 64];
  const int h = blockIdx.x, win = blockIdx.y;  // h fastest
  const int l = threadIdx.x, lr = l & 15, lq = l >> 4;
  const bf16_t* qbase = qkv + (size_t)win * 64 * 1152 + h * 32;

  // stage V transposed (swizzled cols); visibility ensured by pre-PV barrier
  {
    const bf16_t* vrow = qbase + l * 1152 + 768;
#pragma unroll
    for (int c = 0; c < 4; c++) {
      bf16x8 tv = *(const bf16x8*)&vrow[c * 8];
#pragma unroll
      for (int e = 0; e < 8; e++) {
        int vr = c * 8 + e;
        Vt[vr * 64 + (l ^ ((vr & 7) << 3))] = tv[e];
      }
    }
  }

  // S = Q K^T  (64x64, K=32); Q pre-scaled via weight fold; direct loads
  f32x4 sacc[4][4] = {};
  {
    bf16x8 a[4], b[4];
#pragma unroll
    for (int fi = 0; fi < 4; fi++)
      a[fi] = *(const bf16x8*)(qbase + (size_t)(fi * 16 + lr) * 1152 + lq * 8);
#pragma unroll
    for (int fj = 0; fj < 4; fj++)
      b[fj] = *(const bf16x8*)(qbase + 384 + (size_t)(fj * 16 + lr) * 1152 + lq * 8);
    __builtin_amdgcn_s_setprio(1);
#pragma unroll
    for (int fi = 0; fi < 4; fi++)
#pragma unroll
      for (int fj = 0; fj < 4; fj++)
        sacc[fi][fj] = mfma16(a[fi], b[fj], sacc[fi][fj]);
    __builtin_amdgcn_s_setprio(0);
  }

  // softmax with precomputed bf16 bias+mask table
  const int widx = win & 63;
  const int cls = (((widx >> 3) == 7) << 1) | ((widx & 7) == 7);
  const bf16_t* bfp = biasF + (((size_t)cls * 12 + h) << 12);
#pragma unroll
  for (int fi = 0; fi < 4; fi++) {
#pragma unroll
    for (int reg = 0; reg < 4; reg++) {
      int row = fi * 16 + lq * 4 + reg;  // C/D: row=(l>>4)*4+reg (+fi*16)
      const bf16_t* brow = bfp + row * 64 + lr;
      float vals[4], m = -1e30f;
#pragma unroll
      for (int fj = 0; fj < 4; fj++) {
        float v = sacc[fi][fj][reg] + (float)brow[fj * 16];
        vals[fj] = v;
        m = fmaxf(m, v);
      }
#pragma unroll
      for (int o = 1; o < 16; o <<= 1) m = fmaxf(m, __shfl_xor(m, o));
      float ssum = 0.f;
#pragma unroll
      for (int fj = 0; fj < 4; fj++) {
        vals[fj] = __expf(vals[fj] - m);
        ssum += vals[fj];
      }
#pragma unroll
      for (int o = 1; o < 16; o <<= 1) ssum += __shfl_xor(ssum, o);
      float inv = 1.f / ssum;
      int sw = (row & 7) << 3;
#pragma unroll
      for (int fj = 0; fj < 4; fj++)
        Ps[row * 64 + ((fj * 16 + lr) ^ sw)] = (bf16_t)(vals[fj] * inv);
    }
  }
  __syncthreads();  // orders Vt + Ps writes before the reads below

  // O = P V  (64x32, K=64); swizzled Ps / Vt reads (conflict-free)
  f32x4 oacc[4][2] = {};
#pragma unroll
  for (int kc = 0; kc < 2; kc++) {
    bf16x8 pa[4], vb[2];
#pragma unroll
    for (int fi = 0; fi < 4; fi++) {
      int row = fi * 16 + lr;
      pa[fi] = *(const bf16x8*)&Ps[row * 64 + ((kc * 32 + lq * 8) ^ ((row & 7) << 3))];
    }
#pragma unroll
    for (int fj = 0; fj < 2; fj++) {
      int row = fj * 16 + lr;
      vb[fj] = *(const bf16x8*)&Vt[row * 64 + ((kc * 32 + lq * 8) ^ ((row & 7) << 3))];
    }
    __builtin_amdgcn_s_setprio(1);
#pragma unroll
    for (int fi = 0; fi < 4; fi++)
#pragma unroll
      for (int fj = 0; fj < 2; fj++)
        oacc[fi][fj] = mfma16(pa[fi], vb[fj], oacc[fi][fj]);
    __builtin_amdgcn_s_setprio(0);
  }
#pragma unroll
  for (int fi = 0; fi < 4; fi++)
#pragma unroll
    for (int reg = 0; reg < 4; reg++) {
      int row = fi * 16 + lq * 4 + reg;
      size_t rb = ((size_t)win * 64 + row) * 384 + h * 32;
#pragma unroll
      for (int fj = 0; fj < 2; fj++)
        aout[rb + fj * 16 + lr] = (bf16_t)oacc[fi][fj][reg];
    }
}

// ---------------------------------------------------------------------------
extern "C" void kernel_launch(void* const* d_in, const int* in_sizes, int n_in,
                              void* d_out, int out_size, void* d_ws, size_t ws_size,
                              hipStream_t stream) {
  (void)in_sizes; (void)n_in; (void)out_size; (void)ws_size;
  const float* x      = (const float*)d_in[0];
  const float* gamma1 = (const float*)d_in[1];
  const float* beta1  = (const float*)d_in[2];
  const float* w_qkv  = (const float*)d_in[3];
  const float* b_qkv  = (const float*)d_in[4];
  const float* btab   = (const float*)d_in[5];
  const float* w_proj = (const float*)d_in[6];
  const float* b_proj = (const float*)d_in[7];
  const float* gamma2 = (const float*)d_in[8];
  const float* beta2  = (const float*)d_in[9];
  const float* w_fc1  = (const float*)d_in[10];
  const float* b_fc1  = (const float*)d_in[11];
  const float* w_fc2  = (const float*)d_in[12];
  const float* b_fc2  = (const float*)d_in[13];
  float* out = (float*)d_out;

  char* ws = (char*)d_ws;
  size_t off = 0;
  auto alloc = [&](size_t bytes) {
    void* p = ws + off;
    off += (bytes + 255) & ~(size_t)255;
    return p;
  };
  bf16_t* wqkvT  = (bf16_t*)alloc((size_t)1152 * 384 * 2);
  bf16_t* wprojT = (bf16_t*)alloc((size_t)384 * 384 * 2);
  bf16_t* wfc1T  = (bf16_t*)alloc((size_t)1536 * 384 * 2);
  bf16_t* wfc2T  = (bf16_t*)alloc((size_t)384 * 1536 * 2);
  float*  bqs    = (float*)alloc((size_t)1152 * 4);
  bf16_t* biasF  = (bf16_t*)alloc((size_t)4 * 12 * 4096 * 2);
  // qkv rows [TOK][1152] alias mlp hidden [TOK][1536]; lifetimes disjoint.
  char* big = (char*)alloc((size_t)TOK * 1536 * 2);
  bf16_t* bufA = (bf16_t*)big;  // qkv rows
  bf16_t* bufH = (bf16_t*)big;  // mlp hidden
  bf16_t* bufB = (bf16_t*)alloc((size_t)TOK * 384 * 2);  // ln1/attn/ln2 rows

  // merged prep: weight conversion (+Q-scale fold), scaled b_qkv, bias table
  prep_all<<<(1769472 + 1152 + 196608 + 255) / 256, 256, 0, stream>>>(
      w_qkv, w_proj, w_fc1, w_fc2, b_qkv, btab,
      wqkvT, wprojT, wfc1T, wfc2T, bqs, biasF);

  // LN1 + roll + window partition -> bufB [131072][384] bf16
  ln_kernel<1><<<TOK / 4, 256, 0, stream>>>(x, gamma1, beta1, bufB);
  // QKV: [131072,384] x [384,1152] -> bufA bf16   (grid 9*1024, %8==0)
  gemm_bt<0><<<9 * (TOK / 128), 256, 0, stream>>>(
      bufB, wqkvT, bqs, 384, 1152, 9, bufA, nullptr, nullptr);
  // windowed attention -> bufB [131072][384] bf16  (h fastest)
  attn_kernel<<<dim3(12, NWIN), 64, 0, stream>>>(bufA, biasF, bufB);
  // proj + un-roll scatter + residual(x) -> out (x1, f32)  (grid 3*1024)
  gemm_bt<2><<<3 * (TOK / 128), 256, 0, stream>>>(
      bufB, wprojT, b_proj, 384, 384, 3, nullptr, out, x);
  // LN2 -> bufB bf16
  ln_kernel<0><<<TOK / 4, 256, 0, stream>>>(out, gamma2, beta2, bufB);
  // FC1 + fast GELU -> bufH [131072][1536] bf16  (grid 12*1024)
  gemm_bt<1><<<12 * (TOK / 128), 256, 0, stream>>>(
      bufB, wfc1T, b_fc1, 384, 1536, 12, bufH, nullptr, nullptr);
  // FC2 + residual(out, in-place) -> out  (grid 3*1024)
  gemm_bt<3><<<3 * (TOK / 128), 256, 0, stream>>>(
      bufH, wfc2T, b_fc2, 1536, 384, 3, nullptr, out, out);
}

// Round 17
// 1129.615 us; speedup vs baseline: 1.1499x; 1.0069x over previous
//
#include <hip/hip_runtime.h>
#include <hip/hip_bf16.h>

typedef __bf16 bf16_t;
typedef __bf16 bf16x8 __attribute__((ext_vector_type(8)));
typedef float f32x4 __attribute__((ext_vector_type(4)));

#define DI __device__ __forceinline__

static constexpr int TOK = 131072;  // 32 batches * 64*64 tokens
static constexpr int NWIN = 2048;   // 32 * 64 windows

// window-order token t -> source image token (LN1 gather) == proj scatter dest.
DI int src_token(int t) {
  int b = t >> 12;
  int widx = (t >> 6) & 63;
  int n = t & 63;
  int wh = widx >> 3, ww = widx & 7;
  int i = n >> 3, j = n & 7;
  int y = ((wh << 3) + i + 4) & 63;
  int x2 = ((ww << 3) + j + 4) & 63;
  return (b << 12) + (y << 6) + x2;
}

DI f32x4 mfma16(bf16x8 a, bf16x8 b, f32x4 c) {
  return __builtin_amdgcn_mfma_f32_16x16x32_bf16(a, b, c, 0, 0, 0);
}

DI void gload_lds16(const bf16_t* g, bf16_t* l) {
  __builtin_amdgcn_global_load_lds(
      (__attribute__((address_space(1))) void*)const_cast<bf16_t*>(g),
      (__attribute__((address_space(3))) void*)l, 16, 0, 0);
}

// ------ merged prep: weight transpose+convert (+Q-scale fold) + scaled b_qkv
//        + bias_full table (bf16), all in ONE launch ------
__global__ void prep_all(const float* __restrict__ wq, const float* __restrict__ wp,
                         const float* __restrict__ w1, const float* __restrict__ w2,
                         const float* __restrict__ bq, const float* __restrict__ btab,
                         bf16_t* oq, bf16_t* op_, bf16_t* o1, bf16_t* o2,
                         float* bqs, bf16_t* bf) {
  int idx = blockIdx.x * 256 + threadIdx.x;
  const float s = 0.17677669529663687f;  // 32^-0.5
  if (idx < 442368) {
    int n = idx / 384, k = idx - n * 384;
    float v = wq[(size_t)k * 1152 + n];
    if (n < 384) v *= s;
    oq[idx] = (bf16_t)v;
  } else if ((idx -= 442368) < 147456) {
    int n = idx / 384, k = idx - n * 384;
    op_[idx] = (bf16_t)wp[(size_t)k * 384 + n];
  } else if ((idx -= 147456) < 589824) {
    int n = idx / 384, k = idx - n * 384;
    o1[idx] = (bf16_t)w1[(size_t)k * 1536 + n];
  } else if ((idx -= 589824) < 589824) {
    int n = idx / 1536, k = idx - n * 1536;
    o2[idx] = (bf16_t)w2[(size_t)k * 384 + n];
  } else if ((idx -= 589824) < 1152) {
    bqs[idx] = bq[idx] * (idx < 384 ? s : 1.f);
  } else if ((idx -= 1152) < 4 * 12 * 4096) {
    // bias_full[4 classes][12 heads][64][64] = rel_bias + shift-mask, bf16.
    int c = idx & 63, r = (idx >> 6) & 63;
    int hh = idx >> 12;
    int h = hh % 12, cls = hh / 12;
    int i1 = r >> 3, j1 = r & 7, i2 = c >> 3, j2 = c & 7;
    float v = btab[((i1 - i2 + 7) * 15 + (j1 - j2 + 7)) * 12 + h];
    int wh7 = cls >> 1, ww7 = cls & 1;
    int ly1 = wh7 ? (i1 >= 4 ? 2 : 1) : 0;
    int ly2 = wh7 ? (i2 >= 4 ? 2 : 1) : 0;
    int lx1 = ww7 ? (j1 >= 4 ? 2 : 1) : 0;
    int lx2 = ww7 ? (j2 >= 4 ? 2 : 1) : 0;
    if (ly1 != ly2 || lx1 != lx2) v -= 100.f;
    bf[idx] = (bf16_t)v;
  }
}

// ---------------- LayerNorm (+optional shift/partition gather), f32 -> bf16 --
template <int MAP>
__global__ __launch_bounds__(256)
void ln_kernel(const float* __restrict__ xin, const float* __restrict__ g,
               const float* __restrict__ be, bf16_t* __restrict__ out) {
  int w = threadIdx.x >> 6, l = threadIdx.x & 63;
  int t = blockIdx.x * 4 + w;
  int s = MAP ? src_token(t) : t;
  const float* row = xin + (size_t)s * 384;
  float v[6], s1 = 0.f, s2 = 0.f;
#pragma unroll
  for (int i = 0; i < 6; i++) {
    v[i] = row[l + i * 64];
    s1 += v[i];
    s2 += v[i] * v[i];
  }
#pragma unroll
  for (int o = 32; o; o >>= 1) {
    s1 += __shfl_xor(s1, o);
    s2 += __shfl_xor(s2, o);
  }
  float mean = s1 * (1.f / 384.f);
  float var = s2 * (1.f / 384.f) - mean * mean;
  float rs = rsqrtf(var + 1e-5f);
  bf16_t* orow = out + (size_t)t * 384;
#pragma unroll
  for (int i = 0; i < 6; i++) {
    int idx = l + i * 64;
    orow[idx] = (bf16_t)((v[i] - mean) * rs * g[idx] + be[idx]);
  }
}

// ---------------- GEMM: C[M][N] = A[M][K]*Wt[N][K]^T + bias ------------------
// r13-proven core FROZEN: single-buffered 32KB LDS, BK=64, 2 barriers/K-tile,
// both-sides XOR swizzle, XCD-chunked remap, VALU diet.
// MODE 1: bf16 gelu(out). 2: f32 scatter(src_token)+resid. 3: f32 +resid.
// MODE 4: QKV epilogue -> compact per-head tiles q/k/v[12][2048][64][32] bf16
//         (store segments identical to row-major; attn loads become dense).
template <int MODE>
__global__ __launch_bounds__(256, 4)
void gemm_bt(const bf16_t* __restrict__ A, const bf16_t* __restrict__ Wt,
             const float* __restrict__ bias, int K, int ldout, int ncols,
             bf16_t* outb, float* outf, const float* resid,
             bf16_t* qout, bf16_t* kout, bf16_t* vout) {
  __shared__ __align__(16) bf16_t Alds[128 * 64];
  __shared__ __align__(16) bf16_t Blds[128 * 64];
  const int tid = threadIdx.x;
  const int l = tid & 63, w = tid >> 6;
  const int lr = l & 15, lq = l >> 4;
  const int nwg = gridDim.x;
  const int orig = blockIdx.x;
  const int wgid = (orig & 7) * (nwg >> 3) + (orig >> 3);
  const int bn = wgid % ncols, bm = wgid / ncols;
  const int wr = w >> 1, wc = w & 1;

  const int srow = w * 8 + (l >> 3);
  const int scol = ((l & 7) ^ (l >> 3)) << 3;
  const bf16_t* ga = A + ((size_t)bm * 128 + srow) * K + scol;
  const bf16_t* gb = Wt + ((size_t)bn * 128 + srow) * K + scol;
  const size_t k32 = (size_t)32 * K;
  bf16_t* la = &Alds[w * 512];
  bf16_t* lb = &Blds[w * 512];

  int aoff[8], boff[8];
#pragma unroll
  for (int fi = 0; fi < 4; fi++) {
    int ra = wr * 64 + fi * 16 + lr;
    int rb = wc * 64 + fi * 16 + lr;
#pragma unroll
    for (int ks = 0; ks < 2; ks++) {
      aoff[fi * 2 + ks] = ra * 64 + ((ks * 32 + lq * 8) ^ ((ra & 7) << 3));
      boff[fi * 2 + ks] = rb * 64 + ((ks * 32 + lq * 8) ^ ((rb & 7) << 3));
    }
  }

  f32x4 acc[4][4] = {};
  const int nt = K >> 6;
  for (int t = 0; t < nt; t++) {
#pragma unroll
    for (int r = 0; r < 4; r++) {
      gload_lds16(ga + r * k32, la + r * 2048);
      gload_lds16(gb + r * k32, lb + r * 2048);
    }
    ga += 64;
    gb += 64;
    __syncthreads();
#pragma unroll
    for (int ks = 0; ks < 2; ks++) {
      bf16x8 af[4], bfr[4];
#pragma unroll
      for (int fi = 0; fi < 4; fi++)
        af[fi] = *(const bf16x8*)&Alds[aoff[fi * 2 + ks]];
#pragma unroll
      for (int fj = 0; fj < 4; fj++)
        bfr[fj] = *(const bf16x8*)&Blds[boff[fj * 2 + ks]];
#pragma unroll
      for (int fi = 0; fi < 4; fi++)
#pragma unroll
        for (int fj = 0; fj < 4; fj++)
          acc[fi][fj] = mfma16(af[fi], bfr[fj], acc[fi][fj]);
    }
    __syncthreads();
  }

  float bv[4];
#pragma unroll
  for (int fj = 0; fj < 4; fj++)
    bv[fj] = bias[bn * 128 + wc * 64 + fj * 16 + lr];

  if constexpr (MODE == 4) {
    // sel/h/d decomposition: gcol = bn*128+wc*64+fj*16+lr, 384 cols per sel.
    bf16_t* dstb = (bn < 3) ? qout : (bn < 6) ? kout : vout;
    const int h0 = (bn % 3) * 4 + wc * 2;  // + (fj>>1)
    const int win = bm * 2 + wr;
#pragma unroll
    for (int fi = 0; fi < 4; fi++) {
#pragma unroll
      for (int reg = 0; reg < 4; reg++) {
        int tok = fi * 16 + lq * 4 + reg;
#pragma unroll
        for (int fj = 0; fj < 4; fj++) {
          int h = h0 + (fj >> 1);
          float val = acc[fi][fj][reg] + bv[fj];
          dstb[((((size_t)h * NWIN + win) * 64 + tok) << 5) + (fj & 1) * 16 + lr] =
              (bf16_t)val;
        }
      }
    }
    return;
  }

#pragma unroll
  for (int fi = 0; fi < 4; fi++) {
#pragma unroll
    for (int reg = 0; reg < 4; reg++) {
      int grow = bm * 128 + wr * 64 + fi * 16 + lq * 4 + reg;
      size_t rbase;
      if constexpr (MODE == 2)
        rbase = (size_t)src_token(grow) * ldout;
      else
        rbase = (size_t)grow * ldout;
#pragma unroll
      for (int fj = 0; fj < 4; fj++) {
        int gcol = bn * 128 + wc * 64 + fj * 16 + lr;
        float val = acc[fi][fj][reg] + bv[fj];
        if constexpr (MODE == 1) {
          // tanh-form GELU via fast sigmoid (rcp instead of div)
          float z = -1.5957691216f * val * fmaf(0.044715f, val * val, 1.0f);
          val = val * __builtin_amdgcn_rcpf(1.0f + __expf(z));
          outb[rbase + gcol] = (bf16_t)val;
        } else if constexpr (MODE == 2 || MODE == 3) {
          outf[rbase + gcol] = val + resid[rbase + gcol];
        } else {
          outb[rbase + gcol] = (bf16_t)val;
        }
      }
    }
  }
}

// ---------------- per-(window, head) attention ------------------------------
// Compact per-head Q/K/V tiles [64][32] (4KB each): every fragment load is a
// DENSE contiguous 1KB block (16 rows x 64B) — 4x fewer cache lines than the
// old 2304B-strided reads. win-fastest grid streams each head's contiguous
// window run. bf16 bias table + T5 setprio kept from r16.
__global__ __launch_bounds__(64)
void attn_kernel(const bf16_t* __restrict__ qb, const bf16_t* __restrict__ kb,
                 const bf16_t* __restrict__ vb, const bf16_t* __restrict__ biasF,
                 bf16_t* __restrict__ aout) {
  __shared__ __align__(16) bf16_t Vt[32 * 64];
  __shared__ __align__(16) bf16_t Ps[64 * 64];
  const int win = blockIdx.x, h = blockIdx.y;  // win fastest
  const int l = threadIdx.x, lr = l & 15, lq = l >> 4;
  const size_t tile = ((size_t)h * NWIN + win) << 11;  // 64*32 elems
  const bf16_t* qt = qb + tile;
  const bf16_t* kt = kb + tile;
  const bf16_t* vt = vb + tile;

  // stage V transposed (swizzled cols); visibility ensured by pre-PV barrier
  {
    const bf16_t* vrow = vt + l * 32;
#pragma unroll
    for (int c = 0; c < 4; c++) {
      bf16x8 tv = *(const bf16x8*)&vrow[c * 8];
#pragma unroll
      for (int e = 0; e < 8; e++) {
        int vr = c * 8 + e;
        Vt[vr * 64 + (l ^ ((vr & 7) << 3))] = tv[e];
      }
    }
  }

  // S = Q K^T  (64x64, K=32); Q pre-scaled via weight fold; dense loads
  f32x4 sacc[4][4] = {};
  {
    bf16x8 a[4], b[4];
#pragma unroll
    for (int fi = 0; fi < 4; fi++)
      a[fi] = *(const bf16x8*)(qt + (fi * 16 + lr) * 32 + lq * 8);
#pragma unroll
    for (int fj = 0; fj < 4; fj++)
      b[fj] = *(const bf16x8*)(kt + (fj * 16 + lr) * 32 + lq * 8);
    __builtin_amdgcn_s_setprio(1);
#pragma unroll
    for (int fi = 0; fi < 4; fi++)
#pragma unroll
      for (int fj = 0; fj < 4; fj++)
        sacc[fi][fj] = mfma16(a[fi], b[fj], sacc[fi][fj]);
    __builtin_amdgcn_s_setprio(0);
  }

  // softmax with precomputed bf16 bias+mask table
  const int widx = win & 63;
  const int cls = (((widx >> 3) == 7) << 1) | ((widx & 7) == 7);
  const bf16_t* bfp = biasF + (((size_t)cls * 12 + h) << 12);
#pragma unroll
  for (int fi = 0; fi < 4; fi++) {
#pragma unroll
    for (int reg = 0; reg < 4; reg++) {
      int row = fi * 16 + lq * 4 + reg;  // C/D: row=(l>>4)*4+reg (+fi*16)
      const bf16_t* brow = bfp + row * 64 + lr;
      float vals[4], m = -1e30f;
#pragma unroll
      for (int fj = 0; fj < 4; fj++) {
        float v = sacc[fi][fj][reg] + (float)brow[fj * 16];
        vals[fj] = v;
        m = fmaxf(m, v);
      }
#pragma unroll
      for (int o = 1; o < 16; o <<= 1) m = fmaxf(m, __shfl_xor(m, o));
      float ssum = 0.f;
#pragma unroll
      for (int fj = 0; fj < 4; fj++) {
        vals[fj] = __expf(vals[fj] - m);
        ssum += vals[fj];
      }
#pragma unroll
      for (int o = 1; o < 16; o <<= 1) ssum += __shfl_xor(ssum, o);
      float inv = 1.f / ssum;
      int sw = (row & 7) << 3;
#pragma unroll
      for (int fj = 0; fj < 4; fj++)
        Ps[row * 64 + ((fj * 16 + lr) ^ sw)] = (bf16_t)(vals[fj] * inv);
    }
  }
  __syncthreads();  // orders Vt + Ps writes before the reads below

  // O = P V  (64x32, K=64); swizzled Ps / Vt reads (conflict-free)
  f32x4 oacc[4][2] = {};
#pragma unroll
  for (int kc = 0; kc < 2; kc++) {
    bf16x8 pa[4], vbf[2];
#pragma unroll
    for (int fi = 0; fi < 4; fi++) {
      int row = fi * 16 + lr;
      pa[fi] = *(const bf16x8*)&Ps[row * 64 + ((kc * 32 + lq * 8) ^ ((row & 7) << 3))];
    }
#pragma unroll
    for (int fj = 0; fj < 2; fj++) {
      int row = fj * 16 + lr;
      vbf[fj] = *(const bf16x8*)&Vt[row * 64 + ((kc * 32 + lq * 8) ^ ((row & 7) << 3))];
    }
    __builtin_amdgcn_s_setprio(1);
#pragma unroll
    for (int fi = 0; fi < 4; fi++)
#pragma unroll
      for (int fj = 0; fj < 2; fj++)
        oacc[fi][fj] = mfma16(pa[fi], vbf[fj], oacc[fi][fj]);
    __builtin_amdgcn_s_setprio(0);
  }
#pragma unroll
  for (int fi = 0; fi < 4; fi++)
#pragma unroll
    for (int reg = 0; reg < 4; reg++) {
      int row = fi * 16 + lq * 4 + reg;
      size_t rb = ((size_t)win * 64 + row) * 384 + h * 32;
#pragma unroll
      for (int fj = 0; fj < 2; fj++)
        aout[rb + fj * 16 + lr] = (bf16_t)oacc[fi][fj][reg];
    }
}

// ---------------------------------------------------------------------------
extern "C" void kernel_launch(void* const* d_in, const int* in_sizes, int n_in,
                              void* d_out, int out_size, void* d_ws, size_t ws_size,
                              hipStream_t stream) {
  (void)in_sizes; (void)n_in; (void)out_size; (void)ws_size;
  const float* x      = (const float*)d_in[0];
  const float* gamma1 = (const float*)d_in[1];
  const float* beta1  = (const float*)d_in[2];
  const float* w_qkv  = (const float*)d_in[3];
  const float* b_qkv  = (const float*)d_in[4];
  const float* btab   = (const float*)d_in[5];
  const float* w_proj = (const float*)d_in[6];
  const float* b_proj = (const float*)d_in[7];
  const float* gamma2 = (const float*)d_in[8];
  const float* beta2  = (const float*)d_in[9];
  const float* w_fc1  = (const float*)d_in[10];
  const float* b_fc1  = (const float*)d_in[11];
  const float* w_fc2  = (const float*)d_in[12];
  const float* b_fc2  = (const float*)d_in[13];
  float* out = (float*)d_out;

  char* ws = (char*)d_ws;
  size_t off = 0;
  auto alloc = [&](size_t bytes) {
    void* p = ws + off;
    off += (bytes + 255) & ~(size_t)255;
    return p;
  };
  bf16_t* wqkvT  = (bf16_t*)alloc((size_t)1152 * 384 * 2);
  bf16_t* wprojT = (bf16_t*)alloc((size_t)384 * 384 * 2);
  bf16_t* wfc1T  = (bf16_t*)alloc((size_t)1536 * 384 * 2);
  bf16_t* wfc2T  = (bf16_t*)alloc((size_t)384 * 1536 * 2);
  float*  bqs    = (float*)alloc((size_t)1152 * 4);
  bf16_t* biasF  = (bf16_t*)alloc((size_t)4 * 12 * 4096 * 2);
  // q/k/v compact tiles (3 x 100.7MB) alias mlp hidden [TOK][1536] (402.7MB);
  // lifetimes disjoint (qkv: QKV-GEMM..attn; hidden: FC1..FC2).
  char* big = (char*)alloc((size_t)TOK * 1536 * 2);
  bf16_t* qb = (bf16_t*)big;
  bf16_t* kb = (bf16_t*)(big + (size_t)12 * NWIN * 2048 * 2);
  bf16_t* vb = (bf16_t*)(big + (size_t)24 * NWIN * 2048 * 2);
  bf16_t* bufH = (bf16_t*)big;  // mlp hidden
  bf16_t* bufB = (bf16_t*)alloc((size_t)TOK * 384 * 2);  // ln1/attn/ln2 rows

  // merged prep: weight conversion (+Q-scale fold), scaled b_qkv, bias table
  prep_all<<<(1769472 + 1152 + 196608 + 255) / 256, 256, 0, stream>>>(
      w_qkv, w_proj, w_fc1, w_fc2, b_qkv, btab,
      wqkvT, wprojT, wfc1T, wfc2T, bqs, biasF);

  // LN1 + roll + window partition -> bufB [131072][384] bf16
  ln_kernel<1><<<TOK / 4, 256, 0, stream>>>(x, gamma1, beta1, bufB);
  // QKV: [131072,384] x [384,1152] -> compact per-head q/k/v tiles
  gemm_bt<4><<<9 * (TOK / 128), 256, 0, stream>>>(
      bufB, wqkvT, bqs, 384, 0, 9, nullptr, nullptr, nullptr, qb, kb, vb);
  // windowed attention -> bufB [131072][384] bf16  (win fastest)
  attn_kernel<<<dim3(NWIN, 12), 64, 0, stream>>>(qb, kb, vb, biasF, bufB);
  // proj + un-roll scatter + residual(x) -> out (x1, f32)  (grid 3*1024)
  gemm_bt<2><<<3 * (TOK / 128), 256, 0, stream>>>(
      bufB, wprojT, b_proj, 384, 384, 3, nullptr, out, x,
      nullptr, nullptr, nullptr);
  // LN2 -> bufB bf16
  ln_kernel<0><<<TOK / 4, 256, 0, stream>>>(out, gamma2, beta2, bufB);
  // FC1 + fast GELU -> bufH [131072][1536] bf16  (grid 12*1024)
  gemm_bt<1><<<12 * (TOK / 128), 256, 0, stream>>>(
      bufB, wfc1T, b_fc1, 384, 1536, 12, bufH, nullptr, nullptr,
      nullptr, nullptr, nullptr);
  // FC2 + residual(out, in-place) -> out  (grid 3*1024)
  gemm_bt<3><<<3 * (TOK / 128), 256, 0, stream>>>(
      bufH, wfc2T, b_fc2, 1536, 384, 3, nullptr, out, out,
      nullptr, nullptr, nullptr);
}